// Round 5
// baseline (254.464 us; speedup 1.0000x reference)
//
#include <hip/hip_runtime.h>

#define H_ 1080
#define W_ 1920
#define S_ 2000
#define C_ 8
#define HW_ (H_*W_)
#define NQ  (HW_/4)      // 518400 pixel quads, divides 256 exactly? 518400/256 = 2025 ✓
#define ROWF 32          // floats per table row (29 used, pad to 128 B)

// Kernel 1: per superpixel, compute the 29 final float values.
// row[0] = preseg label (float); row[1+4*(j-1)+{0,1,2,3}] =
//   knn_att[j], knn_contrast[j], cent_att[j], cent_contrast[j], j=1..7.
__global__ void build_table_k(const int* __restrict__ knn_pred,
                              const float* __restrict__ knn_dist,
                              const float* __restrict__ cent_dist,
                              float* __restrict__ tab){
  int s = blockIdx.x * blockDim.x + threadIdx.x;
  if (s >= S_) return;
  float kd[C_], cd[C_];
  const float4* kr = reinterpret_cast<const float4*>(knn_dist  + s * C_);
  const float4* cr = reinterpret_cast<const float4*>(cent_dist + s * C_);
  float4 a = kr[0], b = kr[1], c = cr[0], d = cr[1];
  kd[0]=a.x; kd[1]=a.y; kd[2]=a.z; kd[3]=a.w; kd[4]=b.x; kd[5]=b.y; kd[6]=b.z; kd[7]=b.w;
  cd[0]=c.x; cd[1]=c.y; cd[2]=c.z; cd[3]=c.w; cd[4]=d.x; cd[5]=d.y; cd[6]=d.z; cd[7]=d.w;

  float row[ROWF];
  #pragma unroll
  for (int i = 0; i < ROWF; ++i) row[i] = 0.0f;
  row[0] = (float)knn_pred[s];
  #pragma unroll
  for (int j = 1; j < C_; ++j){
    float km = -3.0e38f, cm = -3.0e38f;
    #pragma unroll
    for (int k = 0; k < C_; ++k){
      if (k == j) continue;
      km = fmaxf(km, kd[k]);
      cm = fmaxf(cm, cd[k]);
    }
    int bix = 1 + (j - 1) * 4;
    row[bix + 0] = kd[j];
    row[bix + 1] = km;
    row[bix + 2] = cd[j];
    row[bix + 3] = cm;
  }
  float* g = tab + s * ROWF;
  #pragma unroll
  for (int i = 0; i < ROWF; i += 4)
    *reinterpret_cast<float4*>(g + i) = make_float4(row[i], row[i+1], row[i+2], row[i+3]);
}

// Kernel 2: pure gather/broadcast. 4 pixels/thread: int4 spx load,
// 4 x 8 global_load_dwordx4 row gathers (table 256 KB, L2-resident),
// 29 coalesced float4 plane stores. No LDS, no arithmetic.
__global__ __launch_bounds__(256) void scatter_k(const int* __restrict__ spx,
                                                 const float* __restrict__ tab,
                                                 float* __restrict__ out){
  int t = blockIdx.x * blockDim.x + threadIdx.x;
  int p = t * 4;
  if (p >= HW_) return;
  int4 s4 = *reinterpret_cast<const int4*>(spx + p);
  const float4* r0 = reinterpret_cast<const float4*>(tab + (s4.x - 1) * ROWF);
  const float4* r1 = reinterpret_cast<const float4*>(tab + (s4.y - 1) * ROWF);
  const float4* r2 = reinterpret_cast<const float4*>(tab + (s4.z - 1) * ROWF);
  const float4* r3 = reinterpret_cast<const float4*>(tab + (s4.w - 1) * ROWF);

  float4 a0[8], a1[8], a2[8], a3[8];
  #pragma unroll
  for (int i = 0; i < 8; ++i){ a0[i] = r0[i]; a1[i] = r1[i]; a2[i] = r2[i]; a3[i] = r3[i]; }
  const float* f0 = reinterpret_cast<const float*>(a0);
  const float* f1 = reinterpret_cast<const float*>(a1);
  const float* f2 = reinterpret_cast<const float*>(a2);
  const float* f3 = reinterpret_cast<const float*>(a3);

  #pragma unroll
  for (int m = 0; m < 29; ++m){          // m=0 preseg, m=1..28 attmap planes
    float4 w;
    w.x = f0[m]; w.y = f1[m]; w.z = f2[m]; w.w = f3[m];
    *reinterpret_cast<float4*>(out + (size_t)m * HW_ + p) = w;
  }
}

extern "C" void kernel_launch(void* const* d_in, const int* in_sizes, int n_in,
                              void* d_out, int out_size, void* d_ws, size_t ws_size,
                              hipStream_t stream)
{
  const int*   spx       = (const int*)  d_in[0];   // (1,1,H,W) int32, labels 1..S
  const int*   knn_pred  = (const int*)  d_in[1];   // (S,) int32
  const float* knn_dist  = (const float*)d_in[2];   // (S,C) f32
  const float* cent_dist = (const float*)d_in[3];   // (S,C) f32
  float* out = (float*)d_out;                       // 29*HW float32
  float* tab = (float*)d_ws;                        // 256 KB f32 final-value table

  build_table_k<<<(S_ + 255) / 256, 256, 0, stream>>>(knn_pred, knn_dist, cent_dist, tab);
  scatter_k<<<NQ / 256, 256, 0, stream>>>(spx, tab, out);
}

// Round 6
// 253.882 us; speedup vs baseline: 1.0023x; 1.0023x over previous
//
#include <hip/hip_runtime.h>

#define H_ 1080
#define W_ 1920
#define S_ 2000
#define C_ 8
#define HW_ (H_*W_)
#define NQ  (HW_/4)          // 518400 pixel quads
#define NP  29               // output planes: preseg + 28 attmaps
#define TP  2048             // padded plane-major table row (floats)
#define BPP 405              // blocks per plane; 405*256*5 quads = 518400
#define QPB 1280             // quads per block (5 iters * 256 threads)

typedef unsigned short u16;

// ws layout: [0, 232KB) tabT[29][2048] f32 ; [256KB, ...) idx16[HW] u16
#define IDX_OFF (256*1024)

// Kernel A: per superpixel, compute 29 final values into the PLANE-MAJOR table.
// tabT[m][s]: m=0 preseg label; m=1+4*(j-1)+{0..3} = knn_att[j], knn_contrast[j],
// cent_att[j], cent_contrast[j] for j=1..7 (class labels 2..8).
__global__ void build_tabT_k(const int* __restrict__ knn_pred,
                             const float* __restrict__ knn_dist,
                             const float* __restrict__ cent_dist,
                             float* __restrict__ tabT){
  int s = blockIdx.x * blockDim.x + threadIdx.x;
  if (s >= S_) return;
  float kd[C_], cd[C_];
  const float4* kr = reinterpret_cast<const float4*>(knn_dist  + s * C_);
  const float4* cr = reinterpret_cast<const float4*>(cent_dist + s * C_);
  float4 a = kr[0], b = kr[1], c = cr[0], d = cr[1];
  kd[0]=a.x; kd[1]=a.y; kd[2]=a.z; kd[3]=a.w; kd[4]=b.x; kd[5]=b.y; kd[6]=b.z; kd[7]=b.w;
  cd[0]=c.x; cd[1]=c.y; cd[2]=c.z; cd[3]=c.w; cd[4]=d.x; cd[5]=d.y; cd[6]=d.z; cd[7]=d.w;

  tabT[0 * TP + s] = (float)knn_pred[s];
  #pragma unroll
  for (int j = 1; j < C_; ++j){
    float km = -3.0e38f, cm = -3.0e38f;
    #pragma unroll
    for (int k = 0; k < C_; ++k){
      if (k == j) continue;
      km = fmaxf(km, kd[k]);
      cm = fmaxf(cm, cd[k]);
    }
    int m = 1 + (j - 1) * 4;
    tabT[(m + 0) * TP + s] = kd[j];
    tabT[(m + 1) * TP + s] = km;
    tabT[(m + 2) * TP + s] = cd[j];
    tabT[(m + 3) * TP + s] = cm;
  }
}

// Kernel C: compress spx (int32, 1..S) -> u16 0-based index. 4 px/thread.
__global__ __launch_bounds__(256) void compress_idx_k(const int* __restrict__ spx,
                                                      u16* __restrict__ idx16){
  int t = blockIdx.x * blockDim.x + threadIdx.x;
  int p = t * 4;
  if (p >= HW_) return;
  int4 s4 = *reinterpret_cast<const int4*>(spx + p);
  ushort4 v;
  v.x = (u16)(s4.x - 1); v.y = (u16)(s4.y - 1);
  v.z = (u16)(s4.z - 1); v.w = (u16)(s4.w - 1);
  *reinterpret_cast<ushort4*>(idx16 + p) = v;
}

// Kernel B: plane-sequential broadcast. 1D grid ordered plane-major so the
// chip writes one contiguous 8.3MB plane region at a time (fill-like DRAM
// pattern). Per block: stage this plane's 8KB value row in LDS, then stream
// 1280 quads: ushort4 idx load (L2-resident 4.1MB) -> 4 ds_read_b32 (random
// banks ~2-way, near-free) -> one coalesced float4 store.
__global__ __launch_bounds__(256) void scatter_k(const u16* __restrict__ idx16,
                                                 const float* __restrict__ tabT,
                                                 float* __restrict__ out){
  __shared__ float lds[TP];
  const unsigned bid = blockIdx.x;
  const unsigned m   = bid / BPP;          // plane 0..28
  const unsigned cx  = bid % BPP;          // chunk within plane
  const unsigned tid = threadIdx.x;

  // stage 2048 floats (8KB): 8 per thread, two float4 loads
  {
    const float4* g = reinterpret_cast<const float4*>(tabT + m * TP) + tid * 2;
    float4 v0 = g[0], v1 = g[1];
    float4* l = reinterpret_cast<float4*>(lds) + tid * 2;
    l[0] = v0; l[1] = v1;
  }
  __syncthreads();

  const unsigned qbase = cx * QPB;
  float* op = out + (size_t)m * HW_;
  #pragma unroll
  for (int it = 0; it < 5; ++it){
    unsigned q = qbase + it * 256 + tid;
    ushort4 iv = *reinterpret_cast<const ushort4*>(idx16 + (size_t)q * 4);
    float4 w;
    w.x = lds[iv.x]; w.y = lds[iv.y]; w.z = lds[iv.z]; w.w = lds[iv.w];
    *reinterpret_cast<float4*>(op + (size_t)q * 4) = w;
  }
}

extern "C" void kernel_launch(void* const* d_in, const int* in_sizes, int n_in,
                              void* d_out, int out_size, void* d_ws, size_t ws_size,
                              hipStream_t stream)
{
  const int*   spx       = (const int*)  d_in[0];   // (1,1,H,W) int32, labels 1..S
  const int*   knn_pred  = (const int*)  d_in[1];   // (S,) int32
  const float* knn_dist  = (const float*)d_in[2];   // (S,C) f32
  const float* cent_dist = (const float*)d_in[3];   // (S,C) f32
  float* out   = (float*)d_out;                     // 29*HW float32
  float* tabT  = (float*)d_ws;                      // [29][2048] f32
  u16*   idx16 = (u16*)((char*)d_ws + IDX_OFF);     // [HW] u16

  build_tabT_k<<<(S_ + 255) / 256, 256, 0, stream>>>(knn_pred, knn_dist, cent_dist, tabT);
  compress_idx_k<<<NQ / 256, 256, 0, stream>>>(spx, idx16);
  scatter_k<<<NP * BPP, 256, 0, stream>>>(idx16, tabT, out);
}

// Round 7
// 245.439 us; speedup vs baseline: 1.0368x; 1.0344x over previous
//
#include <hip/hip_runtime.h>

#define H_ 1080
#define W_ 1920
#define S_ 2000
#define C_ 8
#define HW_ (H_*W_)

// Best-measured variant (Round 3, 244.0 us, absmax 0.0).
// Single fused kernel, float32 output. 4 pixels/thread: int4 spx load,
// per-pixel gather of two 32B dist rows (128KB total, L2-resident),
// online top-2 max (tie-safe), 29 coalesced float4 plane stores.
// Rounds 4-6 falsified LDS-table / f32-table / plane-sequential-store
// alternatives (all within +4%): the benchmark window is dominated by
// invariant harness fills + the irreducible 240MB output write.
__global__ __launch_bounds__(256) void fused_k(
    const int*   __restrict__ spx,
    const int*   __restrict__ knn_pred,
    const float* __restrict__ knn_dist,
    const float* __restrict__ cent_dist,
    float*       __restrict__ out)
{
  int t = blockIdx.x * blockDim.x + threadIdx.x;
  int p = t * 4;
  if (p >= HW_) return;

  int4 s4 = *reinterpret_cast<const int4*>(spx + p);
  int idx[4] = { s4.x - 1, s4.y - 1, s4.z - 1, s4.w - 1 };

  // preseg plane (float of int label)
  float4 pv;
  pv.x = (float)knn_pred[idx[0]];
  pv.y = (float)knn_pred[idx[1]];
  pv.z = (float)knn_pred[idx[2]];
  pv.w = (float)knn_pred[idx[3]];
  *reinterpret_cast<float4*>(out + p) = pv;

  // gather the two 8-float rows for each of the 4 pixels (2x float4 each)
  float kd[4][C_], cd[4][C_];
  #pragma unroll
  for (int q = 0; q < 4; ++q) {
    const float4* kr = reinterpret_cast<const float4*>(knn_dist  + idx[q] * C_);
    const float4* cr = reinterpret_cast<const float4*>(cent_dist + idx[q] * C_);
    float4 a = kr[0], b = kr[1], c = cr[0], d = cr[1];
    kd[q][0]=a.x; kd[q][1]=a.y; kd[q][2]=a.z; kd[q][3]=a.w;
    kd[q][4]=b.x; kd[q][5]=b.y; kd[q][6]=b.z; kd[q][7]=b.w;
    cd[q][0]=c.x; cd[q][1]=c.y; cd[q][2]=c.z; cd[q][3]=c.w;
    cd[q][4]=d.x; cd[q][5]=d.y; cd[q][6]=d.z; cd[q][7]=d.w;
  }

  // online top-2 max per row; with duplicates m2==m1, so the contrast
  // select (v==m1 ? m2 : m1) is exact even under ties.
  float km1[4], km2[4], cm1[4], cm2[4];
  #pragma unroll
  for (int q = 0; q < 4; ++q) {
    float m1 = -3.0e38f, m2 = -3.0e38f, n1 = -3.0e38f, n2 = -3.0e38f;
    #pragma unroll
    for (int k = 0; k < C_; ++k) {
      float v = kd[q][k];
      m2 = fmaxf(m2, fminf(v, m1));  m1 = fmaxf(m1, v);
      float u = cd[q][k];
      n2 = fmaxf(n2, fminf(u, n1));  n1 = fmaxf(n1, u);
    }
    km1[q]=m1; km2[q]=m2; cm1[q]=n1; cm2[q]=n2;
  }

  // attmaps planes: [class c=2..8][knn_att, knn_contrast, cent_att, cent_contrast]
  float* ao = out + HW_ + p;
  #pragma unroll
  for (int j = 1; j < C_; ++j) {
    float4 w0, w1, w2, w3;
    w0.x = kd[0][j]; w0.y = kd[1][j]; w0.z = kd[2][j]; w0.w = kd[3][j];
    w1.x = (kd[0][j]==km1[0]) ? km2[0] : km1[0];
    w1.y = (kd[1][j]==km1[1]) ? km2[1] : km1[1];
    w1.z = (kd[2][j]==km1[2]) ? km2[2] : km1[2];
    w1.w = (kd[3][j]==km1[3]) ? km2[3] : km1[3];
    w2.x = cd[0][j]; w2.y = cd[1][j]; w2.z = cd[2][j]; w2.w = cd[3][j];
    w3.x = (cd[0][j]==cm1[0]) ? cm2[0] : cm1[0];
    w3.y = (cd[1][j]==cm1[1]) ? cm2[1] : cm1[1];
    w3.z = (cd[2][j]==cm1[2]) ? cm2[2] : cm1[2];
    w3.w = (cd[3][j]==cm1[3]) ? cm2[3] : cm1[3];

    size_t b = (size_t)(j - 1) * 4 * HW_;
    *reinterpret_cast<float4*>(ao + b            ) = w0;
    *reinterpret_cast<float4*>(ao + b +     HW_  ) = w1;
    *reinterpret_cast<float4*>(ao + b + 2 * HW_  ) = w2;
    *reinterpret_cast<float4*>(ao + b + 3 * HW_  ) = w3;
  }
}

extern "C" void kernel_launch(void* const* d_in, const int* in_sizes, int n_in,
                              void* d_out, int out_size, void* d_ws, size_t ws_size,
                              hipStream_t stream)
{
  const int*   spx       = (const int*)  d_in[0];   // (1,1,H,W) int32, labels 1..S
  const int*   knn_pred  = (const int*)  d_in[1];   // (S,) int32
  const float* knn_dist  = (const float*)d_in[2];   // (S,C) f32
  const float* cent_dist = (const float*)d_in[3];   // (S,C) f32
  float* out = (float*)d_out;                       // 29*HW float32

  const int nthreads = HW_ / 4;                     // 518400, exact
  fused_k<<<(nthreads + 255) / 256, 256, 0, stream>>>(spx, knn_pred, knn_dist, cent_dist, out);
}